// Round 2
// baseline (296.094 us; speedup 1.0000x reference)
//
#include <hip/hip_runtime.h>
#include <hip/hip_bf16.h>

// Problem constants
#define BD   256
#define SD   512
#define HD   768
#define IMGD 2048
#define TWOH 1536
constexpr float EPSV  = 1e-5f;
constexpr float SCALE = 0.036084391824351615f;  // 1/sqrt(768)
constexpr int   SPLIT = 8;
constexpr int   SBLK  = SD / SPLIT;             // 64 rows per block

typedef __attribute__((ext_vector_type(8))) short short8;
typedef __attribute__((ext_vector_type(4))) float f32x4;

__device__ __forceinline__ short f2bs(float x) {
    __hip_bfloat16 h = __float2bfloat16(x);
    return __builtin_bit_cast(short, h);
}

// ---------------------------------------------------------------------------
// Generic small GEMM: C[M,N] = A[M,K] @ B (+bias). TRANSB: B given as [N,K].
// fp32 in/out, bf16 MFMA compute. Tiles 64x64, BK=32, 256 threads (4 waves).
// ---------------------------------------------------------------------------
template<bool TRANSB>
__global__ __launch_bounds__(256) void gemm_k(const float* __restrict__ A,
                                              const float* __restrict__ Bm,
                                              const float* __restrict__ bias,
                                              float* __restrict__ C,
                                              int M, int N, int K) {
    __shared__ __align__(16) __hip_bfloat16 As[64][40];  // [m][k], pad->80B rows
    __shared__ __align__(16) __hip_bfloat16 Bs[64][40];  // [n][k]
    const int tid  = threadIdx.x;
    const int m0   = blockIdx.y * 64, n0 = blockIdx.x * 64;
    const int w    = tid >> 6, lane = tid & 63;
    const int wr   = w >> 1,  wc   = w & 1;
    const int rsel = lane & 15, ks = (lane >> 4) * 8;

    f32x4 zero = {0.f, 0.f, 0.f, 0.f};
    f32x4 acc[2][2] = {{zero, zero}, {zero, zero}};

    for (int k0 = 0; k0 < K; k0 += 32) {
        __syncthreads();
        {   // stage A tile 64x32: thread -> row=tid/4, kchunk=(tid%4)*8
            int row = tid >> 2, kc = (tid & 3) * 8;
            const float* src = &A[(size_t)(m0 + row) * K + k0 + kc];
            float4 v0 = *(const float4*)src;
            float4 v1 = *(const float4*)(src + 4);
            short8 pk;
            pk[0]=f2bs(v0.x); pk[1]=f2bs(v0.y); pk[2]=f2bs(v0.z); pk[3]=f2bs(v0.w);
            pk[4]=f2bs(v1.x); pk[5]=f2bs(v1.y); pk[6]=f2bs(v1.z); pk[7]=f2bs(v1.w);
            *(short8*)&As[row][kc] = pk;
        }
        if (TRANSB) {  // B is [N,K] row-major -> Bs[n][k] stage directly
            int row = tid >> 2, kc = (tid & 3) * 8;
            const float* src = &Bm[(size_t)(n0 + row) * K + k0 + kc];
            float4 v0 = *(const float4*)src;
            float4 v1 = *(const float4*)(src + 4);
            short8 pk;
            pk[0]=f2bs(v0.x); pk[1]=f2bs(v0.y); pk[2]=f2bs(v0.z); pk[3]=f2bs(v0.w);
            pk[4]=f2bs(v1.x); pk[5]=f2bs(v1.y); pk[6]=f2bs(v1.z); pk[7]=f2bs(v1.w);
            *(short8*)&Bs[row][kc] = pk;
        } else {       // B is [K,N] row-major -> transpose into Bs[n][k]
            int kk = tid >> 3, nc = (tid & 7) * 8;
            const float* src = &Bm[(size_t)(k0 + kk) * N + n0 + nc];
            float4 v0 = *(const float4*)src;
            float4 v1 = *(const float4*)(src + 4);
            Bs[nc + 0][kk] = __float2bfloat16(v0.x);
            Bs[nc + 1][kk] = __float2bfloat16(v0.y);
            Bs[nc + 2][kk] = __float2bfloat16(v0.z);
            Bs[nc + 3][kk] = __float2bfloat16(v0.w);
            Bs[nc + 4][kk] = __float2bfloat16(v1.x);
            Bs[nc + 5][kk] = __float2bfloat16(v1.y);
            Bs[nc + 6][kk] = __float2bfloat16(v1.z);
            Bs[nc + 7][kk] = __float2bfloat16(v1.w);
        }
        __syncthreads();
        // A frag: lane holds A[row=lane&15][k=8*(lane>>4)+j]
        short8 a0 = *(const short8*)&As[wr * 32 + rsel][ks];
        short8 a1 = *(const short8*)&As[wr * 32 + 16 + rsel][ks];
        short8 b0 = *(const short8*)&Bs[wc * 32 + rsel][ks];
        short8 b1 = *(const short8*)&Bs[wc * 32 + 16 + rsel][ks];
        acc[0][0] = __builtin_amdgcn_mfma_f32_16x16x32_bf16(a0, b0, acc[0][0], 0, 0, 0);
        acc[0][1] = __builtin_amdgcn_mfma_f32_16x16x32_bf16(a0, b1, acc[0][1], 0, 0, 0);
        acc[1][0] = __builtin_amdgcn_mfma_f32_16x16x32_bf16(a1, b0, acc[1][0], 0, 0, 0);
        acc[1][1] = __builtin_amdgcn_mfma_f32_16x16x32_bf16(a1, b1, acc[1][1], 0, 0, 0);
    }
    // C/D layout: col = lane&15, row = (lane>>4)*4 + reg
    const int colb = lane & 15, rowb = (lane >> 4) * 4;
    #pragma unroll
    for (int fm = 0; fm < 2; ++fm)
        #pragma unroll
        for (int fn = 0; fn < 2; ++fn)
            #pragma unroll
            for (int r = 0; r < 4; ++r) {
                int row = m0 + wr * 32 + fm * 16 + rowb + r;
                int col = n0 + wc * 32 + fn * 16 + colb;
                float v = acc[fm][fn][r];
                if (bias) v += bias[col];
                C[(size_t)row * N + col] = v;
            }
}

// ---------------------------------------------------------------------------
// Streaming flash-style pass over text_features.
// Block = (b, slice): 64 rows. Wave-per-row dot with q~, online softmax
// accumulation of raw tf rows. Partials (m, l, acc[768]) -> ws.
// ---------------------------------------------------------------------------
__global__ __launch_bounds__(256) void stream_attn(const float* __restrict__ tf,
                                                   const float* __restrict__ qt,
                                                   float* __restrict__ pacc) {
    const int bidx = blockIdx.x;
    const int b = bidx / SPLIT, sl = bidx % SPLIT;
    const int tid = threadIdx.x, w = tid >> 6, lane = tid & 63;

    float q[12];
    {
        const float* qp = &qt[b * HD];
        #pragma unroll
        for (int c = 0; c < 3; ++c) {
            float4 v = *(const float4*)&qp[c * 256 + 4 * lane];
            q[c*4+0] = v.x; q[c*4+1] = v.y; q[c*4+2] = v.z; q[c*4+3] = v.w;
        }
    }
    float a[12];
    #pragma unroll
    for (int j = 0; j < 12; ++j) a[j] = 0.f;
    float m = -INFINITY, l = 0.f;

    const int r0 = sl * SBLK + w * (SBLK / 4);  // 16 rows per wave
    for (int i = 0; i < SBLK / 4; ++i) {
        const float* row = &tf[((size_t)b * SD + r0 + i) * HD];
        float t[12];
        #pragma unroll
        for (int c = 0; c < 3; ++c) {
            float4 v = *(const float4*)&row[c * 256 + 4 * lane];
            t[c*4+0] = v.x; t[c*4+1] = v.y; t[c*4+2] = v.z; t[c*4+3] = v.w;
        }
        float p = 0.f;
        #pragma unroll
        for (int j = 0; j < 12; ++j) p = fmaf(t[j], q[j], p);
        #pragma unroll
        for (int off = 32; off > 0; off >>= 1) p += __shfl_xor(p, off);
        float score = p * SCALE;                 // wave-uniform
        if (score <= m) {
            float wt = expf(score - m);
            l += wt;
            #pragma unroll
            for (int j = 0; j < 12; ++j) a[j] = fmaf(wt, t[j], a[j]);
        } else {
            float f = expf(m - score);           // expf(-inf)=0 handles first row
            l = fmaf(l, f, 1.f);
            #pragma unroll
            for (int j = 0; j < 12; ++j) a[j] = fmaf(a[j], f, t[j]);
            m = score;
        }
    }
    // merge 4 waves within block
    __shared__ float sacc[4][HD];
    __shared__ float sm[4], slw[4];
    #pragma unroll
    for (int c = 0; c < 3; ++c)
        #pragma unroll
        for (int j = 0; j < 4; ++j)
            sacc[w][c * 256 + 4 * lane + j] = a[c * 4 + j];
    if (lane == 0) { sm[w] = m; slw[w] = l; }
    __syncthreads();
    float gm = fmaxf(fmaxf(sm[0], sm[1]), fmaxf(sm[2], sm[3]));
    float f0 = expf(sm[0] - gm), f1 = expf(sm[1] - gm);
    float f2 = expf(sm[2] - gm), f3 = expf(sm[3] - gm);
    float gl = f0 * slw[0] + f1 * slw[1] + f2 * slw[2] + f3 * slw[3];
    float* outp = &pacc[(size_t)bidx * (HD + 2)];
    #pragma unroll
    for (int jj = 0; jj < 3; ++jj) {
        int c = jj * 256 + tid;
        outp[c] = f0 * sacc[0][c] + f1 * sacc[1][c] + f2 * sacc[2][c] + f3 * sacc[3][c];
    }
    if (tid == 0) { outp[HD] = gm; outp[HD + 1] = gl; }
}

// Merge SPLIT partials per batch -> ctx_raw[b] = softmax-weighted mean of tf rows
__global__ __launch_bounds__(256) void merge_ctx(const float* __restrict__ pacc,
                                                 float* __restrict__ ctx) {
    const int b = blockIdx.x, tid = threadIdx.x;
    float gm = -INFINITY;
    #pragma unroll
    for (int s = 0; s < SPLIT; ++s)
        gm = fmaxf(gm, pacc[(size_t)(b * SPLIT + s) * (HD + 2) + HD]);
    float gl = 0.f, o0 = 0.f, o1 = 0.f, o2 = 0.f;
    #pragma unroll
    for (int s = 0; s < SPLIT; ++s) {
        const float* pp = &pacc[(size_t)(b * SPLIT + s) * (HD + 2)];
        float f = expf(pp[HD] - gm);
        gl += f * pp[HD + 1];
        o0 += f * pp[tid];
        o1 += f * pp[256 + tid];
        o2 += f * pp[512 + tid];
    }
    float inv = 1.f / gl;
    ctx[b * HD + tid]       = o0 * inv;
    ctx[b * HD + 256 + tid] = o1 * inv;
    ctx[b * HD + 512 + tid] = o2 * inv;
}

__device__ __forceinline__ float block_sum256(float v, float* red, int w, int lane) {
    #pragma unroll
    for (int off = 32; off > 0; off >>= 1) v += __shfl_xor(v, off);
    __syncthreads();
    if (lane == 0) red[w] = v;
    __syncthreads();
    return red[0] + red[1] + red[2] + red[3];
}

// Two LayerNorms + gate softmax + weighted concat -> ws
__global__ __launch_bounds__(256) void fuse_small(const float* __restrict__ icp,
                                                  const float* __restrict__ P,
                                                  const float* __restrict__ iv,
                                                  const float* __restrict__ tf,
                                                  const float* __restrict__ in_g,
                                                  const float* __restrict__ in_b,
                                                  const float* __restrict__ tn_g,
                                                  const float* __restrict__ tn_b,
                                                  const float* __restrict__ Wg,
                                                  const float* __restrict__ bg,
                                                  float* __restrict__ wtd) {
    const int b = blockIdx.x, tid = threadIdx.x;
    const int w = tid >> 6, lane = tid & 63;
    __shared__ float red[4];
    float icv[3], tcv[3];
    #pragma unroll
    for (int j = 0; j < 3; ++j) {
        int c = j * 256 + tid;
        icv[j] = icp[b * HD + c] + P[b * HD + c];
        tcv[j] = iv[b * HD + c] + tf[(size_t)b * SD * HD + c];  // cls = tf[b,0,:]
    }
    float s_i  = block_sum256(icv[0] + icv[1] + icv[2], red, w, lane);
    float ss_i = block_sum256(icv[0]*icv[0] + icv[1]*icv[1] + icv[2]*icv[2], red, w, lane);
    float s_t  = block_sum256(tcv[0] + tcv[1] + tcv[2], red, w, lane);
    float ss_t = block_sum256(tcv[0]*tcv[0] + tcv[1]*tcv[1] + tcv[2]*tcv[2], red, w, lane);
    const float invh = 1.f / HD;
    float mu_i = s_i * invh, var_i = ss_i * invh - mu_i * mu_i;
    float mu_t = s_t * invh, var_t = ss_t * invh - mu_t * mu_t;
    float rs_i = rsqrtf(var_i + EPSV), rs_t = rsqrtf(var_t + EPSV);
    float icn[3], tcn[3];
    #pragma unroll
    for (int j = 0; j < 3; ++j) {
        int c = j * 256 + tid;
        icn[j] = (icv[j] - mu_i) * rs_i * in_g[c] + in_b[c];
        tcn[j] = (tcv[j] - mu_t) * rs_t * tn_g[c] + tn_b[c];
    }
    float z0p = 0.f, z1p = 0.f;
    #pragma unroll
    for (int j = 0; j < 3; ++j) {
        int c = j * 256 + tid;
        z0p += tcn[j] * Wg[c * 2 + 0] + icn[j] * Wg[(HD + c) * 2 + 0];
        z1p += tcn[j] * Wg[c * 2 + 1] + icn[j] * Wg[(HD + c) * 2 + 1];
    }
    float z0 = block_sum256(z0p, red, w, lane) + bg[0];
    float z1 = block_sum256(z1p, red, w, lane) + bg[1];
    float mx = fmaxf(z0, z1);
    float e0 = expf(z0 - mx), e1 = expf(z1 - mx);
    float inv = 1.f / (e0 + e1);
    float g0 = e0 * inv, g1 = e1 * inv;
    #pragma unroll
    for (int j = 0; j < 3; ++j) {
        int c = j * 256 + tid;
        wtd[(size_t)b * TWOH + c]      = tcn[j] * g0;
        wtd[(size_t)b * TWOH + HD + c] = icn[j] * g1;
    }
}

// Final LayerNorm + exact gelu -> fp32 out (reference output dtype is float32!)
__global__ __launch_bounds__(256) void final_ln_gelu(const float* __restrict__ y,
                                                     const float* __restrict__ fn_g,
                                                     const float* __restrict__ fn_b,
                                                     float* __restrict__ out) {
    const int b = blockIdx.x, tid = threadIdx.x;
    const int w = tid >> 6, lane = tid & 63;
    __shared__ float red[4];
    float v[3];
    #pragma unroll
    for (int j = 0; j < 3; ++j) v[j] = y[b * HD + j * 256 + tid];
    float s  = block_sum256(v[0] + v[1] + v[2], red, w, lane);
    float ss = block_sum256(v[0]*v[0] + v[1]*v[1] + v[2]*v[2], red, w, lane);
    const float invh = 1.f / HD;
    float mu = s * invh, var = ss * invh - mu * mu;
    float rs = rsqrtf(var + EPSV);
    #pragma unroll
    for (int j = 0; j < 3; ++j) {
        int c = j * 256 + tid;
        float x = (v[j] - mu) * rs * fn_g[c] + fn_b[c];
        float g = 0.5f * x * (1.f + erff(x * 0.7071067811865476f));
        out[b * HD + c] = g;
    }
}

// ---------------------------------------------------------------------------
extern "C" void kernel_launch(void* const* d_in, const int* in_sizes, int n_in,
                              void* d_out, int out_size, void* d_ws, size_t ws_size,
                              hipStream_t stream) {
    const float* tf   = (const float*)d_in[0];
    const float* imgf = (const float*)d_in[1];
    const float* Wp   = (const float*)d_in[2];
    const float* bp   = (const float*)d_in[3];
    // d_in[4..7] (Wtq,btq,Wik,bik): dead — t_attn == 1 exactly (softmax over 1 elem)
    const float* Wiv  = (const float*)d_in[8];
    const float* biv  = (const float*)d_in[9];
    const float* Wiq  = (const float*)d_in[10];
    const float* biq  = (const float*)d_in[11];
    const float* Wtk  = (const float*)d_in[12];
    // d_in[13] (btk): adds per-b constant to all scores — softmax-invariant, dropped
    const float* Wtv  = (const float*)d_in[14];
    const float* btv  = (const float*)d_in[15];
    const float* tn_g = (const float*)d_in[16];
    const float* tn_b = (const float*)d_in[17];
    const float* in_g = (const float*)d_in[18];
    const float* in_b = (const float*)d_in[19];
    const float* Wf   = (const float*)d_in[20];
    const float* bff  = (const float*)d_in[21];
    const float* fn_g = (const float*)d_in[22];
    const float* fn_b = (const float*)d_in[23];
    const float* Wg   = (const float*)d_in[24];
    const float* bg   = (const float*)d_in[25];

    float* ws    = (float*)d_ws;
    float* P     = ws;                  // B*H
    float* img_q = P     + BD * HD;
    float* img_v = img_q + BD * HD;
    float* qt    = img_v + BD * HD;
    float* ctx   = qt    + BD * HD;
    float* icp   = ctx   + BD * HD;
    float* yb    = icp   + BD * HD;
    float* wtd   = yb    + BD * HD;     // B*2H
    float* pacc  = wtd   + BD * TWOH;   // B*SPLIT*(H+2)

    dim3 g64(HD / 64, BD / 64);  // (12,4)
    gemm_k<false><<<g64, 256, 0, stream>>>(imgf, Wp, bp, P, BD, HD, IMGD);
    gemm_k<false><<<g64, 256, 0, stream>>>(P, Wiq, biq, img_q, BD, HD, HD);
    gemm_k<false><<<g64, 256, 0, stream>>>(P, Wiv, biv, img_v, BD, HD, HD);
    gemm_k<true ><<<g64, 256, 0, stream>>>(img_q, Wtk, nullptr, qt, BD, HD, HD);
    stream_attn<<<BD * SPLIT, 256, 0, stream>>>(tf, qt, pacc);
    merge_ctx<<<BD, 256, 0, stream>>>(pacc, ctx);
    gemm_k<false><<<g64, 256, 0, stream>>>(ctx, Wtv, btv, icp, BD, HD, HD);
    fuse_small<<<BD, 256, 0, stream>>>(icp, P, img_v, tf, in_g, in_b, tn_g, tn_b,
                                       Wg, bg, wtd);
    gemm_k<false><<<g64, 256, 0, stream>>>(wtd, Wf, bff, yb, BD, HD, TWOH);
    final_ln_gelu<<<BD, 256, 0, stream>>>(yb, fn_g, fn_b, (float*)d_out);
}

// Round 3
// 234.413 us; speedup vs baseline: 1.2631x; 1.2631x over previous
//
#include <hip/hip_runtime.h>
#include <hip/hip_bf16.h>

// Problem constants
#define BD   256
#define SD   512
#define HD   768
#define IMGD 2048
#define TWOH 1536
constexpr float EPSV  = 1e-5f;
constexpr float SCALE = 0.036084391824351615f;  // 1/sqrt(768)
constexpr int   SPLIT = 8;
constexpr int   SBLK  = SD / SPLIT;             // 64 rows per slice

typedef __attribute__((ext_vector_type(8))) short short8;
typedef __attribute__((ext_vector_type(4))) float f32x4;

__device__ __forceinline__ short f2bs(float x) {
    __hip_bfloat16 h = __float2bfloat16(x);
    return __builtin_bit_cast(short, h);
}

struct GemmSmem {
    __hip_bfloat16 As[2][64][40];  // [buf][m][k] padded rows (80B)
    __hip_bfloat16 Bs[2][64][40];  // [buf][n][k]
};

// ---------------------------------------------------------------------------
// 64x64-tile GEMM body, BK=32, double-buffered LDS, 1 barrier per K-step.
// C[M,N] = A[M,K] @ B (+bias). TRANSB: B given as [N,K] row-major.
// Issue next-tile global loads BEFORE MFMA, LDS-commit after (T14 split).
// ---------------------------------------------------------------------------
template<bool TRANSB>
__device__ __forceinline__ void gemm_tile(GemmSmem& smem,
        const float* __restrict__ A, const float* __restrict__ Bm,
        const float* __restrict__ bias, float* __restrict__ C,
        int M, int N, int K, int m0, int n0) {
    const int tid  = threadIdx.x;
    const int w    = tid >> 6, lane = tid & 63;
    const int wr   = w >> 1,  wc   = w & 1;
    const int rsel = lane & 15, ks = (lane >> 4) * 8;
    const int arow = tid >> 2, akc = (tid & 3) * 8;   // A/B(transposed) staging
    const int bkk  = tid >> 3, bnc = (tid & 7) * 8;   // B(normal) staging

    const float* aptr = &A[(size_t)(m0 + arow) * K + akc];
    const float* bptr = TRANSB ? &Bm[(size_t)(n0 + arow) * K + akc]
                               : &Bm[(size_t)bkk * N + n0 + bnc];

    float4 av0, av1, bv0, bv1;
    const int NT = K / 32;

    auto issue = [&](int t) {
        const float* pa = aptr + (size_t)t * 32;
        av0 = *(const float4*)pa;
        av1 = *(const float4*)(pa + 4);
        const float* pb = TRANSB ? (bptr + (size_t)t * 32)
                                 : (bptr + (size_t)t * 32 * N);
        bv0 = *(const float4*)pb;
        bv1 = *(const float4*)(pb + 4);
    };
    auto commit = [&](int buf) {
        short8 pk;
        pk[0]=f2bs(av0.x); pk[1]=f2bs(av0.y); pk[2]=f2bs(av0.z); pk[3]=f2bs(av0.w);
        pk[4]=f2bs(av1.x); pk[5]=f2bs(av1.y); pk[6]=f2bs(av1.z); pk[7]=f2bs(av1.w);
        *(short8*)&smem.As[buf][arow][akc] = pk;
        if (TRANSB) {
            short8 qk;
            qk[0]=f2bs(bv0.x); qk[1]=f2bs(bv0.y); qk[2]=f2bs(bv0.z); qk[3]=f2bs(bv0.w);
            qk[4]=f2bs(bv1.x); qk[5]=f2bs(bv1.y); qk[6]=f2bs(bv1.z); qk[7]=f2bs(bv1.w);
            *(short8*)&smem.Bs[buf][arow][akc] = qk;
        } else {
            smem.Bs[buf][bnc + 0][bkk] = __float2bfloat16(bv0.x);
            smem.Bs[buf][bnc + 1][bkk] = __float2bfloat16(bv0.y);
            smem.Bs[buf][bnc + 2][bkk] = __float2bfloat16(bv0.z);
            smem.Bs[buf][bnc + 3][bkk] = __float2bfloat16(bv0.w);
            smem.Bs[buf][bnc + 4][bkk] = __float2bfloat16(bv1.x);
            smem.Bs[buf][bnc + 5][bkk] = __float2bfloat16(bv1.y);
            smem.Bs[buf][bnc + 6][bkk] = __float2bfloat16(bv1.z);
            smem.Bs[buf][bnc + 7][bkk] = __float2bfloat16(bv1.w);
        }
    };

    f32x4 zero = {0.f, 0.f, 0.f, 0.f};
    f32x4 acc[2][2] = {{zero, zero}, {zero, zero}};

    issue(0); commit(0);
    __syncthreads();
    int cur = 0;
    for (int t = 0; t < NT; ++t) {
        if (t + 1 < NT) issue(t + 1);
        short8 a0 = *(const short8*)&smem.As[cur][wr * 32 + rsel][ks];
        short8 a1 = *(const short8*)&smem.As[cur][wr * 32 + 16 + rsel][ks];
        short8 b0 = *(const short8*)&smem.Bs[cur][wc * 32 + rsel][ks];
        short8 b1 = *(const short8*)&smem.Bs[cur][wc * 32 + 16 + rsel][ks];
        acc[0][0] = __builtin_amdgcn_mfma_f32_16x16x32_bf16(a0, b0, acc[0][0], 0, 0, 0);
        acc[0][1] = __builtin_amdgcn_mfma_f32_16x16x32_bf16(a0, b1, acc[0][1], 0, 0, 0);
        acc[1][0] = __builtin_amdgcn_mfma_f32_16x16x32_bf16(a1, b0, acc[1][0], 0, 0, 0);
        acc[1][1] = __builtin_amdgcn_mfma_f32_16x16x32_bf16(a1, b1, acc[1][1], 0, 0, 0);
        if (t + 1 < NT) commit(cur ^ 1);
        __syncthreads();
        cur ^= 1;
    }

    // C/D layout: col = lane&15, row = (lane>>4)*4 + reg  [m89-verified]
    const int colb = lane & 15, rowb = (lane >> 4) * 4;
    #pragma unroll
    for (int fm = 0; fm < 2; ++fm)
        #pragma unroll
        for (int fn = 0; fn < 2; ++fn)
            #pragma unroll
            for (int r = 0; r < 4; ++r) {
                int row = m0 + wr * 32 + fm * 16 + rowb + r;
                int col = n0 + wc * 32 + fn * 16 + colb;
                float v = acc[fm][fn][r];
                if (bias) v += bias[col];
                C[(size_t)row * N + col] = v;
            }
}

// ---------------------------------------------------------------------------
// Stage 1 (input-independent parts batched with Wp projection):
//   blocks [0,48):    P   = imgf @ Wp + bp            (256x768, K=2048)
//   blocks [48,192):  Wqk = Wiq @ Wtk^T               (768x768, K=768)
//   blocks [192,204): v1[d] = sum_e biq[e]*Wtk[d,e]   (768-vec matvec)
// ---------------------------------------------------------------------------
__global__ __launch_bounds__(256) void stage1(const float* __restrict__ imgf,
                                              const float* __restrict__ Wp,
                                              const float* __restrict__ bp,
                                              const float* __restrict__ Wiq,
                                              const float* __restrict__ Wtk,
                                              const float* __restrict__ biq,
                                              float* __restrict__ P,
                                              float* __restrict__ Wqk,
                                              float* __restrict__ v1) {
    __shared__ GemmSmem smem;
    const int blk = blockIdx.x;
    if (blk < 48) {
        int m0 = (blk / 12) * 64, n0 = (blk % 12) * 64;
        gemm_tile<false>(smem, imgf, Wp, bp, P, BD, HD, IMGD, m0, n0);
    } else if (blk < 192) {
        int b2 = blk - 48;
        int m0 = (b2 / 12) * 64, n0 = (b2 % 12) * 64;
        gemm_tile<true>(smem, Wiq, Wtk, nullptr, Wqk, HD, HD, HD, m0, n0);
    } else {
        const int b2 = blk - 192;                 // 12 blocks x 64 rows
        const int tid = threadIdx.x, w = tid >> 6, lane = tid & 63;
        float bq[12];
        #pragma unroll
        for (int c = 0; c < 12; ++c) bq[c] = biq[c * 64 + lane];
        const int d0 = b2 * 64 + w * 16;
        for (int i = 0; i < 16; ++i) {
            const float* row = &Wtk[(size_t)(d0 + i) * HD];
            float p = 0.f;
            #pragma unroll
            for (int c = 0; c < 12; ++c) p = fmaf(row[c * 64 + lane], bq[c], p);
            #pragma unroll
            for (int off = 32; off > 0; off >>= 1) p += __shfl_xor(p, off);
            if (lane == 0) v1[d0 + i] = p;
        }
    }
}

// Stage 2: blocks [0,48): qt = P @ Wqk + v1; blocks [48,96): img_v = P @ Wiv + biv
__global__ __launch_bounds__(256) void stage2(const float* __restrict__ Pm,
                                              const float* __restrict__ Wqk,
                                              const float* __restrict__ v1,
                                              const float* __restrict__ Wiv,
                                              const float* __restrict__ biv,
                                              float* __restrict__ qt,
                                              float* __restrict__ img_v) {
    __shared__ GemmSmem smem;
    const int blk = blockIdx.x;
    if (blk < 48) {
        int m0 = (blk / 12) * 64, n0 = (blk % 12) * 64;
        gemm_tile<false>(smem, Pm, Wqk, v1, qt, BD, HD, HD, m0, n0);
    } else {
        int b2 = blk - 48;
        int m0 = (b2 / 12) * 64, n0 = (b2 % 12) * 64;
        gemm_tile<false>(smem, Pm, Wiv, biv, img_v, BD, HD, HD, m0, n0);
    }
}

// Single-problem GEMM wrapper (icp = ctx@Wtv+btv, yb = wtd@Wf+bf)
__global__ __launch_bounds__(256) void gemm_single(const float* __restrict__ A,
                                                   const float* __restrict__ Bm,
                                                   const float* __restrict__ bias,
                                                   float* __restrict__ C,
                                                   int M, int N, int K) {
    __shared__ GemmSmem smem;
    gemm_tile<false>(smem, A, Bm, bias, C, M, N, K,
                     blockIdx.y * 64, blockIdx.x * 64);
}

// ---------------------------------------------------------------------------
// Streaming flash pass over text_features. Grid = 1024 blocks (4/CU resident),
// each handles 2 (b,slice) items. Wave-per-row dot with q~, online softmax
// accumulation of RAW tf rows. Partials (acc[768], m, l) -> pacc.
// ---------------------------------------------------------------------------
__global__ __launch_bounds__(256) void stream_attn(const float* __restrict__ tf,
                                                   const float* __restrict__ qt,
                                                   float* __restrict__ pacc) {
    const int tid = threadIdx.x, w = tid >> 6, lane = tid & 63;
    __shared__ float sacc[4][HD];
    __shared__ float sm_[4], sl_[4];

    for (int item = blockIdx.x; item < BD * SPLIT; item += gridDim.x) {
        const int b = item / SPLIT, sl = item % SPLIT;

        float q[12];
        {
            const float* qp = &qt[b * HD];
            #pragma unroll
            for (int c = 0; c < 3; ++c) {
                float4 v = *(const float4*)&qp[c * 256 + 4 * lane];
                q[c*4+0] = v.x; q[c*4+1] = v.y; q[c*4+2] = v.z; q[c*4+3] = v.w;
            }
        }
        float a[12];
        #pragma unroll
        for (int j = 0; j < 12; ++j) a[j] = 0.f;
        float m = -INFINITY, l = 0.f;

        const int r0 = sl * SBLK + w * (SBLK / 4);  // 16 rows per wave
        for (int i = 0; i < SBLK / 4; ++i) {
            const float* row = &tf[((size_t)b * SD + r0 + i) * HD];
            float t[12];
            #pragma unroll
            for (int c = 0; c < 3; ++c) {
                float4 v = *(const float4*)&row[c * 256 + 4 * lane];
                t[c*4+0] = v.x; t[c*4+1] = v.y; t[c*4+2] = v.z; t[c*4+3] = v.w;
            }
            float p = 0.f;
            #pragma unroll
            for (int j = 0; j < 12; ++j) p = fmaf(t[j], q[j], p);
            #pragma unroll
            for (int off = 32; off > 0; off >>= 1) p += __shfl_xor(p, off);
            float score = p * SCALE;                 // wave-uniform
            if (score <= m) {
                float wt = expf(score - m);
                l += wt;
                #pragma unroll
                for (int j = 0; j < 12; ++j) a[j] = fmaf(wt, t[j], a[j]);
            } else {
                float f = expf(m - score);           // expf(-inf)=0: first row
                l = fmaf(l, f, 1.f);
                #pragma unroll
                for (int j = 0; j < 12; ++j) a[j] = fmaf(a[j], f, t[j]);
                m = score;
            }
        }
        // merge 4 waves
        #pragma unroll
        for (int c = 0; c < 3; ++c)
            #pragma unroll
            for (int j = 0; j < 4; ++j)
                sacc[w][c * 256 + 4 * lane + j] = a[c * 4 + j];
        if (lane == 0) { sm_[w] = m; sl_[w] = l; }
        __syncthreads();
        float gm = fmaxf(fmaxf(sm_[0], sm_[1]), fmaxf(sm_[2], sm_[3]));
        float f0 = expf(sm_[0] - gm), f1 = expf(sm_[1] - gm);
        float f2 = expf(sm_[2] - gm), f3 = expf(sm_[3] - gm);
        float gl = f0 * sl_[0] + f1 * sl_[1] + f2 * sl_[2] + f3 * sl_[3];
        float* outp = &pacc[(size_t)item * (HD + 2)];
        #pragma unroll
        for (int jj = 0; jj < 3; ++jj) {
            int c = jj * 256 + tid;
            outp[c] = f0 * sacc[0][c] + f1 * sacc[1][c] + f2 * sacc[2][c] + f3 * sacc[3][c];
        }
        if (tid == 0) { outp[HD] = gm; outp[HD + 1] = gl; }
        __syncthreads();   // sacc reused by next item
    }
}

// Merge SPLIT partials per batch -> ctx[b]
__global__ __launch_bounds__(256) void merge_ctx(const float* __restrict__ pacc,
                                                 float* __restrict__ ctx) {
    const int b = blockIdx.x, tid = threadIdx.x;
    float gm = -INFINITY;
    #pragma unroll
    for (int s = 0; s < SPLIT; ++s)
        gm = fmaxf(gm, pacc[(size_t)(b * SPLIT + s) * (HD + 2) + HD]);
    float gl = 0.f, o0 = 0.f, o1 = 0.f, o2 = 0.f;
    #pragma unroll
    for (int s = 0; s < SPLIT; ++s) {
        const float* pp = &pacc[(size_t)(b * SPLIT + s) * (HD + 2)];
        float f = expf(pp[HD] - gm);
        gl += f * pp[HD + 1];
        o0 += f * pp[tid];
        o1 += f * pp[256 + tid];
        o2 += f * pp[512 + tid];
    }
    float inv = 1.f / gl;
    ctx[b * HD + tid]       = o0 * inv;
    ctx[b * HD + 256 + tid] = o1 * inv;
    ctx[b * HD + 512 + tid] = o2 * inv;
}

__device__ __forceinline__ float block_sum256(float v, float* red, int w, int lane) {
    #pragma unroll
    for (int off = 32; off > 0; off >>= 1) v += __shfl_xor(v, off);
    __syncthreads();
    if (lane == 0) red[w] = v;
    __syncthreads();
    return red[0] + red[1] + red[2] + red[3];
}

// Two LayerNorms + gate softmax + weighted concat -> wtd
__global__ __launch_bounds__(256) void fuse_small(const float* __restrict__ icp,
                                                  const float* __restrict__ P,
                                                  const float* __restrict__ iv,
                                                  const float* __restrict__ tf,
                                                  const float* __restrict__ in_g,
                                                  const float* __restrict__ in_b,
                                                  const float* __restrict__ tn_g,
                                                  const float* __restrict__ tn_b,
                                                  const float* __restrict__ Wg,
                                                  const float* __restrict__ bg,
                                                  float* __restrict__ wtd) {
    const int b = blockIdx.x, tid = threadIdx.x;
    const int w = tid >> 6, lane = tid & 63;
    __shared__ float red[4];
    float icv[3], tcv[3];
    #pragma unroll
    for (int j = 0; j < 3; ++j) {
        int c = j * 256 + tid;
        icv[j] = icp[b * HD + c] + P[b * HD + c];
        tcv[j] = iv[b * HD + c] + tf[(size_t)b * SD * HD + c];  // cls = tf[b,0,:]
    }
    float s_i  = block_sum256(icv[0] + icv[1] + icv[2], red, w, lane);
    float ss_i = block_sum256(icv[0]*icv[0] + icv[1]*icv[1] + icv[2]*icv[2], red, w, lane);
    float s_t  = block_sum256(tcv[0] + tcv[1] + tcv[2], red, w, lane);
    float ss_t = block_sum256(tcv[0]*tcv[0] + tcv[1]*tcv[1] + tcv[2]*tcv[2], red, w, lane);
    const float invh = 1.f / HD;
    float mu_i = s_i * invh, var_i = ss_i * invh - mu_i * mu_i;
    float mu_t = s_t * invh, var_t = ss_t * invh - mu_t * mu_t;
    float rs_i = rsqrtf(var_i + EPSV), rs_t = rsqrtf(var_t + EPSV);
    float icn[3], tcn[3];
    #pragma unroll
    for (int j = 0; j < 3; ++j) {
        int c = j * 256 + tid;
        icn[j] = (icv[j] - mu_i) * rs_i * in_g[c] + in_b[c];
        tcn[j] = (tcv[j] - mu_t) * rs_t * tn_g[c] + tn_b[c];
    }
    float z0p = 0.f, z1p = 0.f;
    #pragma unroll
    for (int j = 0; j < 3; ++j) {
        int c = j * 256 + tid;
        z0p += tcn[j] * Wg[c * 2 + 0] + icn[j] * Wg[(HD + c) * 2 + 0];
        z1p += tcn[j] * Wg[c * 2 + 1] + icn[j] * Wg[(HD + c) * 2 + 1];
    }
    float z0 = block_sum256(z0p, red, w, lane) + bg[0];
    float z1 = block_sum256(z1p, red, w, lane) + bg[1];
    float mx = fmaxf(z0, z1);
    float e0 = expf(z0 - mx), e1 = expf(z1 - mx);
    float inv = 1.f / (e0 + e1);
    float g0 = e0 * inv, g1 = e1 * inv;
    #pragma unroll
    for (int j = 0; j < 3; ++j) {
        int c = j * 256 + tid;
        wtd[(size_t)b * TWOH + c]      = tcn[j] * g0;
        wtd[(size_t)b * TWOH + HD + c] = icn[j] * g1;
    }
}

// Final LayerNorm + exact gelu -> fp32 out
__global__ __launch_bounds__(256) void final_ln_gelu(const float* __restrict__ y,
                                                     const float* __restrict__ fn_g,
                                                     const float* __restrict__ fn_b,
                                                     float* __restrict__ out) {
    const int b = blockIdx.x, tid = threadIdx.x;
    const int w = tid >> 6, lane = tid & 63;
    __shared__ float red[4];
    float v[3];
    #pragma unroll
    for (int j = 0; j < 3; ++j) v[j] = y[b * HD + j * 256 + tid];
    float s  = block_sum256(v[0] + v[1] + v[2], red, w, lane);
    float ss = block_sum256(v[0]*v[0] + v[1]*v[1] + v[2]*v[2], red, w, lane);
    const float invh = 1.f / HD;
    float mu = s * invh, var = ss * invh - mu * mu;
    float rs = rsqrtf(var + EPSV);
    #pragma unroll
    for (int j = 0; j < 3; ++j) {
        int c = j * 256 + tid;
        float x = (v[j] - mu) * rs * fn_g[c] + fn_b[c];
        float g = 0.5f * x * (1.f + erff(x * 0.7071067811865476f));
        out[b * HD + c] = g;
    }
}

// ---------------------------------------------------------------------------
extern "C" void kernel_launch(void* const* d_in, const int* in_sizes, int n_in,
                              void* d_out, int out_size, void* d_ws, size_t ws_size,
                              hipStream_t stream) {
    const float* tf   = (const float*)d_in[0];
    const float* imgf = (const float*)d_in[1];
    const float* Wp   = (const float*)d_in[2];
    const float* bp   = (const float*)d_in[3];
    // d_in[4..7] (Wtq,btq,Wik,bik): dead — softmax over 1 element == 1 exactly
    const float* Wiv  = (const float*)d_in[8];
    const float* biv  = (const float*)d_in[9];
    const float* Wiq  = (const float*)d_in[10];
    const float* biq  = (const float*)d_in[11];
    const float* Wtk  = (const float*)d_in[12];
    // d_in[13] (btk): per-b constant on scores — softmax-invariant, dropped
    const float* Wtv  = (const float*)d_in[14];
    const float* btv  = (const float*)d_in[15];
    const float* tn_g = (const float*)d_in[16];
    const float* tn_b = (const float*)d_in[17];
    const float* in_g = (const float*)d_in[18];
    const float* in_b = (const float*)d_in[19];
    const float* Wf   = (const float*)d_in[20];
    const float* bff  = (const float*)d_in[21];
    const float* fn_g = (const float*)d_in[22];
    const float* fn_b = (const float*)d_in[23];
    const float* Wg   = (const float*)d_in[24];
    const float* bg   = (const float*)d_in[25];

    float* ws    = (float*)d_ws;
    float* P     = ws;                    // B*H
    float* Wqk   = P     + BD * HD;       // H*H
    float* v1    = Wqk   + HD * HD;       // H
    float* qt    = v1    + HD;            // B*H
    float* img_v = qt    + BD * HD;       // B*H
    float* ctx   = img_v + BD * HD;       // B*H
    float* icp   = ctx   + BD * HD;       // B*H
    float* yb    = icp   + BD * HD;       // B*H
    float* wtd   = yb    + BD * HD;       // B*2H
    float* pacc  = wtd   + BD * TWOH;     // B*SPLIT*(H+2)

    stage1<<<204, 256, 0, stream>>>(imgf, Wp, bp, Wiq, Wtk, biq, P, Wqk, v1);
    stage2<<<96, 256, 0, stream>>>(P, Wqk, v1, Wiv, biv, qt, img_v);
    stream_attn<<<1024, 256, 0, stream>>>(tf, qt, pacc);
    merge_ctx<<<BD, 256, 0, stream>>>(pacc, ctx);
    gemm_single<<<dim3(HD / 64, BD / 64), 256, 0, stream>>>(ctx, Wtv, btv, icp,
                                                            BD, HD, HD);
    fuse_small<<<BD, 256, 0, stream>>>(icp, P, img_v, tf, in_g, in_b, tn_g, tn_b,
                                       Wg, bg, wtd);
    gemm_single<<<dim3(HD / 64, BD / 64), 256, 0, stream>>>(wtd, Wf, bff, yb,
                                                            BD, HD, TWOH);
    final_ln_gelu<<<BD, 256, 0, stream>>>(yb, fn_g, fn_b, (float*)d_out);
}

// Round 4
// 145.287 us; speedup vs baseline: 2.0380x; 1.6135x over previous
//
#include <hip/hip_runtime.h>
#include <hip/hip_bf16.h>

// Problem constants
#define BD   256
#define SD   512
#define HD   768
#define IMGD 2048
#define TWOH 1536
constexpr float EPSV  = 1e-5f;
constexpr float SCALE = 0.036084391824351615f;  // 1/sqrt(768)
constexpr int   SPLIT = 8;
constexpr int   SBLK  = SD / SPLIT;             // 64 rows per slice

typedef __attribute__((ext_vector_type(8))) short short8;
typedef __attribute__((ext_vector_type(4))) float f32x4;

__device__ __forceinline__ short f2bs(float x) {
    __hip_bfloat16 h = __float2bfloat16(x);
    return __builtin_bit_cast(short, h);
}
__device__ __forceinline__ float4 f4sum(float4 a, float4 b) {
    return make_float4(a.x + b.x, a.y + b.y, a.z + b.z, a.w + b.w);
}

struct GemmSmem {
    __hip_bfloat16 As[2][64][40];  // [buf][m][k] padded rows (80B: 2-way-max read)
    __hip_bfloat16 Bs[2][64][40];  // [buf][n][k]
};

// ---------------------------------------------------------------------------
// 64x64-tile GEMM core, BK=32, double LDS buffer + depth-2 register prefetch:
// tile t+2's global loads are issued at iter t, committed to LDS at iter t+1,
// consumed at iter t+2 -> ~1.5 iterations of latency slack before any wait.
// ALoad/BLoad lambdas deliver two float4s per thread per tile (may sum
// split-K partials from producers). TRANSB: B staged as [N,K] rows.
// ---------------------------------------------------------------------------
template<bool TRANSB, class AF, class BF>
__device__ __forceinline__ void gemm_core(GemmSmem& smem, AF aload, BF bload,
        const float* __restrict__ bias, float* __restrict__ C,
        int N, int m0, int n0, int NT) {
    const int tid  = threadIdx.x;
    const int w    = tid >> 6, lane = tid & 63;
    const int wr   = w >> 1,  wc   = w & 1;
    const int rsel = lane & 15, ks = (lane >> 4) * 8;
    const int arow = tid >> 2, akc = (tid & 3) * 8;
    const int bkk  = tid >> 3, bnc = (tid & 7) * 8;

    float4 a0v[2], a1v[2], b0v[2], b1v[2];   // two prefetch slots (tile t in slot t&1)

    auto issue = [&](int slot, int t) {
        aload(t, a0v[slot], a1v[slot]);
        bload(t, b0v[slot], b1v[slot]);
    };
    auto commit = [&](int buf, int slot) {
        short8 pk;
        pk[0]=f2bs(a0v[slot].x); pk[1]=f2bs(a0v[slot].y);
        pk[2]=f2bs(a0v[slot].z); pk[3]=f2bs(a0v[slot].w);
        pk[4]=f2bs(a1v[slot].x); pk[5]=f2bs(a1v[slot].y);
        pk[6]=f2bs(a1v[slot].z); pk[7]=f2bs(a1v[slot].w);
        *(short8*)&smem.As[buf][arow][akc] = pk;
        if (TRANSB) {
            short8 qk;
            qk[0]=f2bs(b0v[slot].x); qk[1]=f2bs(b0v[slot].y);
            qk[2]=f2bs(b0v[slot].z); qk[3]=f2bs(b0v[slot].w);
            qk[4]=f2bs(b1v[slot].x); qk[5]=f2bs(b1v[slot].y);
            qk[6]=f2bs(b1v[slot].z); qk[7]=f2bs(b1v[slot].w);
            *(short8*)&smem.Bs[buf][arow][akc] = qk;
        } else {
            smem.Bs[buf][bnc + 0][bkk] = __float2bfloat16(b0v[slot].x);
            smem.Bs[buf][bnc + 1][bkk] = __float2bfloat16(b0v[slot].y);
            smem.Bs[buf][bnc + 2][bkk] = __float2bfloat16(b0v[slot].z);
            smem.Bs[buf][bnc + 3][bkk] = __float2bfloat16(b0v[slot].w);
            smem.Bs[buf][bnc + 4][bkk] = __float2bfloat16(b1v[slot].x);
            smem.Bs[buf][bnc + 5][bkk] = __float2bfloat16(b1v[slot].y);
            smem.Bs[buf][bnc + 6][bkk] = __float2bfloat16(b1v[slot].z);
            smem.Bs[buf][bnc + 7][bkk] = __float2bfloat16(b1v[slot].w);
        }
    };

    f32x4 zero = {0.f, 0.f, 0.f, 0.f};
    f32x4 acc[2][2] = {{zero, zero}, {zero, zero}};

    issue(0, 0);
    commit(0, 0);                 // one unavoidable cold vmcnt(0) wait
    if (NT > 1) issue(1, 1);
    __syncthreads();

    for (int t = 0; t < NT; ++t) {
        const int cur = t & 1;
        short8 A0 = *(const short8*)&smem.As[cur][wr * 32 + rsel][ks];
        short8 A1 = *(const short8*)&smem.As[cur][wr * 32 + 16 + rsel][ks];
        short8 B0 = *(const short8*)&smem.Bs[cur][wc * 32 + rsel][ks];
        short8 B1 = *(const short8*)&smem.Bs[cur][wc * 32 + 16 + rsel][ks];
        if (t + 1 < NT) commit(cur ^ 1, (t + 1) & 1);   // loads from iter t-1
        if (t + 2 < NT) issue(cur, t + 2);              // slot t&1 now free
        acc[0][0] = __builtin_amdgcn_mfma_f32_16x16x32_bf16(A0, B0, acc[0][0], 0, 0, 0);
        acc[0][1] = __builtin_amdgcn_mfma_f32_16x16x32_bf16(A0, B1, acc[0][1], 0, 0, 0);
        acc[1][0] = __builtin_amdgcn_mfma_f32_16x16x32_bf16(A1, B0, acc[1][0], 0, 0, 0);
        acc[1][1] = __builtin_amdgcn_mfma_f32_16x16x32_bf16(A1, B1, acc[1][1], 0, 0, 0);
        __syncthreads();
    }

    // C/D layout: col = lane&15, row = (lane>>4)*4 + reg  [m89-verified]
    const int colb = lane & 15, rowb = (lane >> 4) * 4;
    #pragma unroll
    for (int fm = 0; fm < 2; ++fm)
        #pragma unroll
        for (int fn = 0; fn < 2; ++fn)
            #pragma unroll
            for (int r = 0; r < 4; ++r) {
                int row = m0 + wr * 32 + fm * 16 + rowb + r;
                int col = n0 + wc * 32 + fn * 16 + colb;
                float v = acc[fm][fn][r];
                if (bias) v += bias[col];
                C[(size_t)row * N + col] = v;
            }
}

// ---------------------------------------------------------------------------
// Stage 1:
//  blocks [0,192):   P_p   = imgf @ Wp  split-K x4 (K=512 each) + bp in p=0
//  blocks [192,480): Wqk_p = Wiq @ Wtk^T split-K x2 (K=384 each)
//  blocks [480,492): v1[d] = sum_e biq[e]*Wtk[d,e]
// ---------------------------------------------------------------------------
__global__ __launch_bounds__(256) void stage1(const float* __restrict__ imgf,
                                              const float* __restrict__ Wp,
                                              const float* __restrict__ bp,
                                              const float* __restrict__ Wiq,
                                              const float* __restrict__ Wtk,
                                              const float* __restrict__ biq,
                                              float* __restrict__ Pp,
                                              float* __restrict__ Wqkp,
                                              float* __restrict__ v1) {
    __shared__ GemmSmem smem;
    const int blk = blockIdx.x, tid = threadIdx.x;
    const int arow = tid >> 2, akc = (tid & 3) * 8;
    const int bkk  = tid >> 3, bnc = (tid & 7) * 8;
    if (blk < 192) {
        const int part = blk / 48, tile = blk % 48;
        const int m0 = (tile / 12) * 64, n0 = (tile % 12) * 64, kbeg = part * 512;
        const float* ap = &imgf[(size_t)(m0 + arow) * IMGD + kbeg + akc];
        const float* bq = &Wp[(size_t)(kbeg + bkk) * HD + n0 + bnc];
        auto al = [&](int t, float4& v0, float4& v1_) {
            const float* p = ap + t * 32;
            v0 = *(const float4*)p; v1_ = *(const float4*)(p + 4);
        };
        auto bl = [&](int t, float4& v0, float4& v1_) {
            const float* p = bq + (size_t)t * 32 * HD;
            v0 = *(const float4*)p; v1_ = *(const float4*)(p + 4);
        };
        gemm_core<false>(smem, al, bl, part == 0 ? bp : nullptr,
                         Pp + (size_t)part * BD * HD, HD, m0, n0, 16);
    } else if (blk < 480) {
        const int b2 = blk - 192, part = b2 / 144, tile = b2 % 144;
        const int m0 = (tile / 12) * 64, n0 = (tile % 12) * 64, kbeg = part * 384;
        const float* ap = &Wiq[(size_t)(m0 + arow) * HD + kbeg + akc];
        const float* bq = &Wtk[(size_t)(n0 + arow) * HD + kbeg + akc];
        auto al = [&](int t, float4& v0, float4& v1_) {
            const float* p = ap + t * 32;
            v0 = *(const float4*)p; v1_ = *(const float4*)(p + 4);
        };
        auto bl = [&](int t, float4& v0, float4& v1_) {
            const float* p = bq + t * 32;
            v0 = *(const float4*)p; v1_ = *(const float4*)(p + 4);
        };
        gemm_core<true>(smem, al, bl, nullptr,
                        Wqkp + (size_t)part * HD * HD, HD, m0, n0, 12);
    } else {
        const int b2 = blk - 480;               // 12 blocks x 64 rows
        const int w = tid >> 6, lane = tid & 63;
        float bq[12];
        #pragma unroll
        for (int c = 0; c < 12; ++c) bq[c] = biq[c * 64 + lane];
        const int d0 = b2 * 64 + w * 16;
        for (int i = 0; i < 16; ++i) {
            const float* row = &Wtk[(size_t)(d0 + i) * HD];
            float p = 0.f;
            #pragma unroll
            for (int c = 0; c < 12; ++c) p = fmaf(row[c * 64 + lane], bq[c], p);
            #pragma unroll
            for (int off = 32; off > 0; off >>= 1) p += __shfl_xor(p, off);
            if (lane == 0) v1[d0 + i] = p;
        }
    }
}

// Stage 2: qt_p = (SUM P) @ (SUM Wqk) split-K x2 (+v1 in p=0);
//          iv_p = (SUM P) @ Wiv split-K x2 (+biv in p=0)
__global__ __launch_bounds__(256) void stage2(const float* __restrict__ Pp,
                                              const float* __restrict__ Wqkp,
                                              const float* __restrict__ v1,
                                              const float* __restrict__ Wiv,
                                              const float* __restrict__ biv,
                                              float* __restrict__ qtp,
                                              float* __restrict__ ivp) {
    __shared__ GemmSmem smem;
    const int blk = blockIdx.x, tid = threadIdx.x;
    const int arow = tid >> 2, akc = (tid & 3) * 8;
    const int bkk  = tid >> 3, bnc = (tid & 7) * 8;
    const bool isqt = blk < 96;
    const int b2 = isqt ? blk : blk - 96;
    const int part = b2 / 48, tile = b2 % 48;
    const int m0 = (tile / 12) * 64, n0 = (tile % 12) * 64, kbeg = part * 384;

    const float* ap = &Pp[(size_t)(m0 + arow) * HD + kbeg + akc];
    auto al = [&](int t, float4& v0, float4& v1_) {          // A = sum of 4 P parts
        const float* p = ap + t * 32;
        float4 x0 = *(const float4*)p, x1 = *(const float4*)(p + 4);
        #pragma unroll
        for (int q = 1; q < 4; ++q) {
            const float* r = p + (size_t)q * BD * HD;
            x0 = f4sum(x0, *(const float4*)r);
            x1 = f4sum(x1, *(const float4*)(r + 4));
        }
        v0 = x0; v1_ = x1;
    };
    if (isqt) {
        const float* bq = &Wqkp[(size_t)(kbeg + bkk) * HD + n0 + bnc];
        auto bl = [&](int t, float4& v0, float4& v1_) {      // B = sum of 2 Wqk parts
            const float* p = bq + (size_t)t * 32 * HD;
            v0 = f4sum(*(const float4*)p, *(const float4*)(p + (size_t)HD * HD));
            v1_ = f4sum(*(const float4*)(p + 4), *(const float4*)(p + (size_t)HD * HD + 4));
        };
        gemm_core<false>(smem, al, bl, part == 0 ? v1 : nullptr,
                         qtp + (size_t)part * BD * HD, HD, m0, n0, 12);
    } else {
        const float* bq = &Wiv[(size_t)(kbeg + bkk) * HD + n0 + bnc];
        auto bl = [&](int t, float4& v0, float4& v1_) {
            const float* p = bq + (size_t)t * 32 * HD;
            v0 = *(const float4*)p; v1_ = *(const float4*)(p + 4);
        };
        gemm_core<false>(smem, al, bl, part == 0 ? biv : nullptr,
                         ivp + (size_t)part * BD * HD, HD, m0, n0, 12);
    }
}

// icp_p = ctx @ Wtv split-K x2 (+btv in p=0)
__global__ __launch_bounds__(256) void gemm_ctxv(const float* __restrict__ ctx,
                                                 const float* __restrict__ Wtv,
                                                 const float* __restrict__ btv,
                                                 float* __restrict__ icpp) {
    __shared__ GemmSmem smem;
    const int tid = threadIdx.x;
    const int arow = tid >> 2, akc = (tid & 3) * 8;
    const int bkk  = tid >> 3, bnc = (tid & 7) * 8;
    const int part = blockIdx.x / 48, tile = blockIdx.x % 48;
    const int m0 = (tile / 12) * 64, n0 = (tile % 12) * 64, kbeg = part * 384;
    const float* ap = &ctx[(size_t)(m0 + arow) * HD + kbeg + akc];
    const float* bq = &Wtv[(size_t)(kbeg + bkk) * HD + n0 + bnc];
    auto al = [&](int t, float4& v0, float4& v1_) {
        const float* p = ap + t * 32;
        v0 = *(const float4*)p; v1_ = *(const float4*)(p + 4);
    };
    auto bl = [&](int t, float4& v0, float4& v1_) {
        const float* p = bq + (size_t)t * 32 * HD;
        v0 = *(const float4*)p; v1_ = *(const float4*)(p + 4);
    };
    gemm_core<false>(smem, al, bl, part == 0 ? btv : nullptr,
                     icpp + (size_t)part * BD * HD, HD, m0, n0, 12);
}

// yb_p = wtd @ Wf split-K x4 (+bf in p=0)
__global__ __launch_bounds__(256) void gemm_wf(const float* __restrict__ wtd,
                                               const float* __restrict__ Wf,
                                               const float* __restrict__ bf,
                                               float* __restrict__ ybp) {
    __shared__ GemmSmem smem;
    const int tid = threadIdx.x;
    const int arow = tid >> 2, akc = (tid & 3) * 8;
    const int bkk  = tid >> 3, bnc = (tid & 7) * 8;
    const int part = blockIdx.x / 48, tile = blockIdx.x % 48;
    const int m0 = (tile / 12) * 64, n0 = (tile % 12) * 64, kbeg = part * 384;
    const float* ap = &wtd[(size_t)(m0 + arow) * TWOH + kbeg + akc];
    const float* bq = &Wf[(size_t)(kbeg + bkk) * HD + n0 + bnc];
    auto al = [&](int t, float4& v0, float4& v1_) {
        const float* p = ap + t * 32;
        v0 = *(const float4*)p; v1_ = *(const float4*)(p + 4);
    };
    auto bl = [&](int t, float4& v0, float4& v1_) {
        const float* p = bq + (size_t)t * 32 * HD;
        v0 = *(const float4*)p; v1_ = *(const float4*)(p + 4);
    };
    gemm_core<false>(smem, al, bl, part == 0 ? bf : nullptr,
                     ybp + (size_t)part * BD * HD, HD, m0, n0, 12);
}

// ---------------------------------------------------------------------------
// Streaming flash pass over text_features. Grid = 1024 (4 blocks/CU), each
// handles 2 (b,slice) items. q~ = qt0 + qt1 (split-K partial merge on load).
// ---------------------------------------------------------------------------
__global__ __launch_bounds__(256) void stream_attn(const float* __restrict__ tf,
                                                   const float* __restrict__ qtp,
                                                   float* __restrict__ pacc) {
    const int tid = threadIdx.x, w = tid >> 6, lane = tid & 63;
    __shared__ float sacc[4][HD];
    __shared__ float sm_[4], sl_[4];

    for (int item = blockIdx.x; item < BD * SPLIT; item += gridDim.x) {
        const int b = item / SPLIT, sl = item % SPLIT;

        float q[12];
        {
            const float* qp0 = &qtp[b * HD];
            const float* qp1 = qp0 + (size_t)BD * HD;
            #pragma unroll
            for (int c = 0; c < 3; ++c) {
                float4 v = f4sum(*(const float4*)&qp0[c * 256 + 4 * lane],
                                 *(const float4*)&qp1[c * 256 + 4 * lane]);
                q[c*4+0] = v.x; q[c*4+1] = v.y; q[c*4+2] = v.z; q[c*4+3] = v.w;
            }
        }
        float a[12];
        #pragma unroll
        for (int j = 0; j < 12; ++j) a[j] = 0.f;
        float m = -INFINITY, l = 0.f;

        const int r0 = sl * SBLK + w * (SBLK / 4);  // 16 rows per wave
        for (int i = 0; i < SBLK / 4; ++i) {
            const float* row = &tf[((size_t)b * SD + r0 + i) * HD];
            float t[12];
            #pragma unroll
            for (int c = 0; c < 3; ++c) {
                float4 v = *(const float4*)&row[c * 256 + 4 * lane];
                t[c*4+0] = v.x; t[c*4+1] = v.y; t[c*4+2] = v.z; t[c*4+3] = v.w;
            }
            float p = 0.f;
            #pragma unroll
            for (int j = 0; j < 12; ++j) p = fmaf(t[j], q[j], p);
            #pragma unroll
            for (int off = 32; off > 0; off >>= 1) p += __shfl_xor(p, off);
            float score = p * SCALE;                 // wave-uniform
            if (score <= m) {
                float wt = expf(score - m);
                l += wt;
                #pragma unroll
                for (int j = 0; j < 12; ++j) a[j] = fmaf(wt, t[j], a[j]);
            } else {
                float f = expf(m - score);           // expf(-inf)=0: first row
                l = fmaf(l, f, 1.f);
                #pragma unroll
                for (int j = 0; j < 12; ++j) a[j] = fmaf(a[j], f, t[j]);
                m = score;
            }
        }
        // merge 4 waves
        #pragma unroll
        for (int c = 0; c < 3; ++c)
            #pragma unroll
            for (int j = 0; j < 4; ++j)
                sacc[w][c * 256 + 4 * lane + j] = a[c * 4 + j];
        if (lane == 0) { sm_[w] = m; sl_[w] = l; }
        __syncthreads();
        float gm = fmaxf(fmaxf(sm_[0], sm_[1]), fmaxf(sm_[2], sm_[3]));
        float f0 = expf(sm_[0] - gm), f1 = expf(sm_[1] - gm);
        float f2 = expf(sm_[2] - gm), f3 = expf(sm_[3] - gm);
        float gl = f0 * sl_[0] + f1 * sl_[1] + f2 * sl_[2] + f3 * sl_[3];
        float* outp = &pacc[(size_t)item * (HD + 2)];
        #pragma unroll
        for (int jj = 0; jj < 3; ++jj) {
            int c = jj * 256 + tid;
            outp[c] = f0 * sacc[0][c] + f1 * sacc[1][c] + f2 * sacc[2][c] + f3 * sacc[3][c];
        }
        if (tid == 0) { outp[HD] = gm; outp[HD + 1] = gl; }
        __syncthreads();   // sacc reused by next item
    }
}

// Merge SPLIT partials per batch -> ctx[b]
__global__ __launch_bounds__(256) void merge_ctx(const float* __restrict__ pacc,
                                                 float* __restrict__ ctx) {
    const int b = blockIdx.x, tid = threadIdx.x;
    float gm = -INFINITY;
    #pragma unroll
    for (int s = 0; s < SPLIT; ++s)
        gm = fmaxf(gm, pacc[(size_t)(b * SPLIT + s) * (HD + 2) + HD]);
    float gl = 0.f, o0 = 0.f, o1 = 0.f, o2 = 0.f;
    #pragma unroll
    for (int s = 0; s < SPLIT; ++s) {
        const float* pp = &pacc[(size_t)(b * SPLIT + s) * (HD + 2)];
        float f = expf(pp[HD] - gm);
        gl += f * pp[HD + 1];
        o0 += f * pp[tid];
        o1 += f * pp[256 + tid];
        o2 += f * pp[512 + tid];
    }
    float inv = 1.f / gl;
    ctx[b * HD + tid]       = o0 * inv;
    ctx[b * HD + 256 + tid] = o1 * inv;
    ctx[b * HD + 512 + tid] = o2 * inv;
}

__device__ __forceinline__ float block_sum256(float v, float* red, int w, int lane) {
    #pragma unroll
    for (int off = 32; off > 0; off >>= 1) v += __shfl_xor(v, off);
    __syncthreads();
    if (lane == 0) red[w] = v;
    __syncthreads();
    return red[0] + red[1] + red[2] + red[3];
}

// Two LayerNorms + gate softmax + weighted concat -> wtd.
// Sums split-K partials: icp x2, P x4, img_v x2.
__global__ __launch_bounds__(256) void fuse_small(const float* __restrict__ icpp,
                                                  const float* __restrict__ Pp,
                                                  const float* __restrict__ ivp,
                                                  const float* __restrict__ tf,
                                                  const float* __restrict__ in_g,
                                                  const float* __restrict__ in_b,
                                                  const float* __restrict__ tn_g,
                                                  const float* __restrict__ tn_b,
                                                  const float* __restrict__ Wg,
                                                  const float* __restrict__ bg,
                                                  float* __restrict__ wtd) {
    const int b = blockIdx.x, tid = threadIdx.x;
    const int w = tid >> 6, lane = tid & 63;
    __shared__ float red[4];
    float icv[3], tcv[3];
    #pragma unroll
    for (int j = 0; j < 3; ++j) {
        int c = j * 256 + tid;
        float pv = 0.f;
        #pragma unroll
        for (int q = 0; q < 4; ++q) pv += Pp[(size_t)q * BD * HD + b * HD + c];
        float ic = icpp[b * HD + c] + icpp[(size_t)BD * HD + b * HD + c];
        icv[j] = ic + pv;
        float iv = ivp[b * HD + c] + ivp[(size_t)BD * HD + b * HD + c];
        tcv[j] = iv + tf[(size_t)b * SD * HD + c];  // cls = tf[b,0,:]
    }
    float s_i  = block_sum256(icv[0] + icv[1] + icv[2], red, w, lane);
    float ss_i = block_sum256(icv[0]*icv[0] + icv[1]*icv[1] + icv[2]*icv[2], red, w, lane);
    float s_t  = block_sum256(tcv[0] + tcv[1] + tcv[2], red, w, lane);
    float ss_t = block_sum256(tcv[0]*tcv[0] + tcv[1]*tcv[1] + tcv[2]*tcv[2], red, w, lane);
    const float invh = 1.f / HD;
    float mu_i = s_i * invh, var_i = ss_i * invh - mu_i * mu_i;
    float mu_t = s_t * invh, var_t = ss_t * invh - mu_t * mu_t;
    float rs_i = rsqrtf(var_i + EPSV), rs_t = rsqrtf(var_t + EPSV);
    float icn[3], tcn[3];
    #pragma unroll
    for (int j = 0; j < 3; ++j) {
        int c = j * 256 + tid;
        icn[j] = (icv[j] - mu_i) * rs_i * in_g[c] + in_b[c];
        tcn[j] = (tcv[j] - mu_t) * rs_t * tn_g[c] + tn_b[c];
    }
    float z0p = 0.f, z1p = 0.f;
    #pragma unroll
    for (int j = 0; j < 3; ++j) {
        int c = j * 256 + tid;
        z0p += tcn[j] * Wg[c * 2 + 0] + icn[j] * Wg[(HD + c) * 2 + 0];
        z1p += tcn[j] * Wg[c * 2 + 1] + icn[j] * Wg[(HD + c) * 2 + 1];
    }
    float z0 = block_sum256(z0p, red, w, lane) + bg[0];
    float z1 = block_sum256(z1p, red, w, lane) + bg[1];
    float mx = fmaxf(z0, z1);
    float e0 = expf(z0 - mx), e1 = expf(z1 - mx);
    float inv = 1.f / (e0 + e1);
    float g0 = e0 * inv, g1 = e1 * inv;
    #pragma unroll
    for (int j = 0; j < 3; ++j) {
        int c = j * 256 + tid;
        wtd[(size_t)b * TWOH + c]      = tcn[j] * g0;
        wtd[(size_t)b * TWOH + HD + c] = icn[j] * g1;
    }
}

// Final LayerNorm + exact gelu -> fp32 out. Sums 4 yb partials.
__global__ __launch_bounds__(256) void final_ln_gelu(const float* __restrict__ ybp,
                                                     const float* __restrict__ fn_g,
                                                     const float* __restrict__ fn_b,
                                                     float* __restrict__ out) {
    const int b = blockIdx.x, tid = threadIdx.x;
    const int w = tid >> 6, lane = tid & 63;
    __shared__ float red[4];
    float v[3];
    #pragma unroll
    for (int j = 0; j < 3; ++j) {
        int c = j * 256 + tid;
        float x = 0.f;
        #pragma unroll
        for (int q = 0; q < 4; ++q) x += ybp[(size_t)q * BD * HD + b * HD + c];
        v[j] = x;
    }
    float s  = block_sum256(v[0] + v[1] + v[2], red, w, lane);
    float ss = block_sum256(v[0]*v[0] + v[1]*v[1] + v[2]*v[2], red, w, lane);
    const float invh = 1.f / HD;
    float mu = s * invh, var = ss * invh - mu * mu;
    float rs = rsqrtf(var + EPSV);
    #pragma unroll
    for (int j = 0; j < 3; ++j) {
        int c = j * 256 + tid;
        float x = (v[j] - mu) * rs * fn_g[c] + fn_b[c];
        float g = 0.5f * x * (1.f + erff(x * 0.7071067811865476f));
        out[b * HD + c] = g;
    }
}

// ---------------------------------------------------------------------------
extern "C" void kernel_launch(void* const* d_in, const int* in_sizes, int n_in,
                              void* d_out, int out_size, void* d_ws, size_t ws_size,
                              hipStream_t stream) {
    const float* tf   = (const float*)d_in[0];
    const float* imgf = (const float*)d_in[1];
    const float* Wp   = (const float*)d_in[2];
    const float* bp   = (const float*)d_in[3];
    // d_in[4..7] (Wtq,btq,Wik,bik): dead — softmax over 1 element == 1 exactly
    const float* Wiv  = (const float*)d_in[8];
    const float* biv  = (const float*)d_in[9];
    const float* Wiq  = (const float*)d_in[10];
    const float* biq  = (const float*)d_in[11];
    const float* Wtk  = (const float*)d_in[12];
    // d_in[13] (btk): per-b constant on scores — softmax-invariant, dropped
    const float* Wtv  = (const float*)d_in[14];
    const float* btv  = (const float*)d_in[15];
    const float* tn_g = (const float*)d_in[16];
    const float* tn_b = (const float*)d_in[17];
    const float* in_g = (const float*)d_in[18];
    const float* in_b = (const float*)d_in[19];
    const float* Wf   = (const float*)d_in[20];
    const float* bff  = (const float*)d_in[21];
    const float* fn_g = (const float*)d_in[22];
    const float* fn_b = (const float*)d_in[23];
    const float* Wg   = (const float*)d_in[24];
    const float* bg   = (const float*)d_in[25];

    float* ws    = (float*)d_ws;
    float* Pp    = ws;                      // 4 * B*H
    float* Wqkp  = Pp    + 4 * BD * HD;     // 2 * H*H
    float* v1    = Wqkp  + 2 * HD * HD;     // H
    float* qtp   = v1    + HD;              // 2 * B*H
    float* ivp   = qtp   + 2 * BD * HD;     // 2 * B*H
    float* ctx   = ivp   + 2 * BD * HD;     // B*H
    float* icpp  = ctx   + BD * HD;         // 2 * B*H
    float* ybp   = icpp  + 2 * BD * HD;     // 4 * B*H
    float* wtd   = ybp   + 4 * BD * HD;     // B*2H
    float* pacc  = wtd   + BD * TWOH;       // B*SPLIT*(H+2)

    stage1<<<492, 256, 0, stream>>>(imgf, Wp, bp, Wiq, Wtk, biq, Pp, Wqkp, v1);
    stage2<<<192, 256, 0, stream>>>(Pp, Wqkp, v1, Wiv, biv, qtp, ivp);
    stream_attn<<<1024, 256, 0, stream>>>(tf, qtp, pacc);
    merge_ctx<<<BD, 256, 0, stream>>>(pacc, ctx);
    gemm_ctxv<<<96, 256, 0, stream>>>(ctx, Wtv, btv, icpp);
    fuse_small<<<BD, 256, 0, stream>>>(icpp, Pp, ivp, tf, in_g, in_b, tn_g, tn_b,
                                       Wg, bg, wtd);
    gemm_wf<<<192, 256, 0, stream>>>(wtd, Wf, bff, ybp);
    final_ln_gelu<<<BD, 256, 0, stream>>>(ybp, fn_g, fn_b, (float*)d_out);
}